// Round 5
// baseline (172.187 us; speedup 1.0000x reference)
//
#include <hip/hip_runtime.h>

#define NF   256   // IN_F
#define HD   256   // H*D
#define NH   4
#define DH   64
#define WINS 128   // WIN
#define HALFW 64
#define TOPK 32
#define GR   8     // rows per gemm block
#define NPB  4     // nodes per attn block (1 per wave)

__device__ __forceinline__ float readlane_f(float v, int l) {
    return __uint_as_float(__builtin_amdgcn_readlane(__float_as_uint(v), l));
}

// ------------- fused Q/K projection: X[n,256] @ W[256,256] + b -------------
// grid (n/GR, 2): y==0 -> Q row-major; y==1 -> K transposed (KT[col][node]).
// X read as block-uniform float4 broadcasts (1 line-request/wave-load);
// W dword loads coalesced. No LDS, no barriers.
__global__ __launch_bounds__(256) void qk_gemm_kernel(
    const float* __restrict__ X,
    const float* __restrict__ Wq, const float* __restrict__ bq,
    const float* __restrict__ Wk, const float* __restrict__ bk,
    float* __restrict__ Qb, float* __restrict__ Kt, int n)
{
    const bool isK = (blockIdx.y != 0);
    const float* W   = isK ? Wk : Wq;
    const float* bia = isK ? bk : bq;

    const int t = threadIdx.x;
    const int rowBase = blockIdx.x * GR;
    const float* Xb = X + (size_t)rowBase * NF;

    float acc[GR];
#pragma unroll
    for (int r = 0; r < GR; ++r) acc[r] = 0.f;

#pragma unroll 4
    for (int k = 0; k < NF; k += 4) {
        float w0 = W[(size_t)(k + 0) * HD + t];
        float w1 = W[(size_t)(k + 1) * HD + t];
        float w2 = W[(size_t)(k + 2) * HD + t];
        float w3 = W[(size_t)(k + 3) * HD + t];
#pragma unroll
        for (int r = 0; r < GR; ++r) {
            float4 f = *(const float4*)(Xb + r * NF + k);   // uniform broadcast
            acc[r] += f.x * w0 + f.y * w1 + f.z * w2 + f.w * w3;
        }
    }
    float bias = bia[t];

    if (!isK) {
#pragma unroll
        for (int r = 0; r < GR; ++r)
            Qb[(size_t)(rowBase + r) * HD + t] = acc[r] + bias;
    } else {
        float4* o = (float4*)(Kt + (size_t)t * n + rowBase);
        o[0] = make_float4(acc[0] + bias, acc[1] + bias, acc[2] + bias, acc[3] + bias);
        o[1] = make_float4(acc[4] + bias, acc[5] + bias, acc[6] + bias, acc[7] + bias);
    }
}

// ---------------------- streaming zero-fill of output ----------------------
__global__ __launch_bounds__(256) void fill_zero_kernel(float4* __restrict__ p, int n4)
{
    int idx = blockIdx.x * 256 + threadIdx.x;
    int stride = gridDim.x * 256;
    float4 z = make_float4(0.f, 0.f, 0.f, 0.f);
    for (int c = idx; c < n4; c += stride) p[c] = z;
}

// ------ per-node attention + top-32, ONE WAVE PER NODE, no barriers ------
// lane l owns window slots {l, l+64}. Scores via KT coalesced dword loads;
// q[d] broadcast via v_readlane. Softmax per head via shfl. Rank via
// per-wave LDS slab. Sparse scatter of 1.0 into pre-zeroed out.
__global__ __launch_bounds__(256) void attn_topk_kernel(
    const float* __restrict__ Q,
    const float* __restrict__ KT,
    const int* __restrict__ nnpg, int n_graphs,
    const int* __restrict__ nrel,
    float* __restrict__ out, int n)
{
    const int t    = threadIdx.x;
    const int wave = t >> 6;
    const int lane = t & 63;
    const int i    = blockIdx.x * NPB + wave;   // this wave's node

    __shared__ float attnv[NPB][WINS];          // per-wave private slab

    // segment bounds: tile(nnpg, R) -> cumsum -> searchsorted(right)
    int R = nrel[0];
    int total = n_graphs * R;
    int seg_start = 0, seg_end = n;
    int cum = 0;
    for (int e = 0; e < total; ++e) {
        int sz = nnpg[e % n_graphs];
        int nc = cum + sz;
        if (i < nc) { seg_start = cum; seg_end = nc; break; }
        cum = nc;
    }
    const int start = max(seg_start, i - HALFW);
    const int end   = min(seg_end,   i + HALFW);
    const int win   = end - start;              // 64..128 for these segments

    // this wave's Q row in registers: lane l holds q[l+64h], h=0..3
    const float* qrow = Q + (size_t)i * HD;
    float qr[NH];
#pragma unroll
    for (int h = 0; h < NH; ++h) qr[h] = qrow[lane + h * DH];

    const bool v0 = (lane      < win);
    const bool v1 = (lane + 64 < win);
    const int  j0 = start + min(lane,      win - 1);   // clamped in-segment
    const int  j1 = start + min(lane + 64, win - 1);

    float mean0 = 0.f, mean1 = 0.f;
#pragma unroll
    for (int h = 0; h < NH; ++h) {
        const float* base = KT + (size_t)(h * DH) * n;
        float a0 = 0.f, a1 = 0.f;
#pragma unroll 8
        for (int d = 0; d < DH; ++d) {
            float qd = readlane_f(qr[h], d);            // SGPR broadcast
            const float* col = base + (size_t)d * n;
            a0 += qd * col[j0];                         // coalesced dword
            a1 += qd * col[j1];
        }
        a0 = v0 ? a0 * 0.25f : 0.f;    // /sqrt(64)/tau; padded slots exactly 0
        a1 = v1 ? a1 * 0.25f : 0.f;

        // softmax over the full 128-slot window (incl. zero padding)
        float mx = fmaxf(a0, a1);
#pragma unroll
        for (int off = 32; off > 0; off >>= 1) mx = fmaxf(mx, __shfl_xor(mx, off));
        float e0 = expf(a0 - mx), e1 = expf(a1 - mx);
        float sm = e0 + e1;
#pragma unroll
        for (int off = 32; off > 0; off >>= 1) sm += __shfl_xor(sm, off);
        float inv = 1.f / sm;
        mean0 += e0 * inv;
        mean1 += e1 * inv;
    }
    mean0 *= 0.25f;
    mean1 *= 0.25f;

    // publish to per-wave slab; invalid slots can never enter top-k
    attnv[wave][lane]      = v0 ? mean0 : -1.0f;
    attnv[wave][lane + 64] = v1 ? mean1 : -1.0f;

    // stable rank count (lower index wins ties, like lax.top_k)
    float w0v = v0 ? mean0 : -1.0f;
    float w1v = v1 ? mean1 : -1.0f;
    int cnt0 = 0, cnt1 = 0;
    const int s0 = lane, s1 = lane + 64;
#pragma unroll
    for (int j4 = 0; j4 < WINS / 4; ++j4) {
        float4 a4 = *(const float4*)&attnv[wave][j4 * 4];  // broadcast b128
        int jb = j4 * 4;
        cnt0 += (a4.x > w0v) || (a4.x == w0v && (jb + 0) < s0);
        cnt0 += (a4.y > w0v) || (a4.y == w0v && (jb + 1) < s0);
        cnt0 += (a4.z > w0v) || (a4.z == w0v && (jb + 2) < s0);
        cnt0 += (a4.w > w0v) || (a4.w == w0v && (jb + 3) < s0);
        cnt1 += (a4.x > w1v) || (a4.x == w1v && (jb + 0) < s1);
        cnt1 += (a4.y > w1v) || (a4.y == w1v && (jb + 1) < s1);
        cnt1 += (a4.z > w1v) || (a4.z == w1v && (jb + 2) < s1);
        cnt1 += (a4.w > w1v) || (a4.w == w1v && (jb + 3) < s1);
    }

    float* orow = out + (size_t)i * n;
    if (v0 && cnt0 < TOPK) orow[start + s0] = 1.0f;
    if (v1 && cnt1 < TOPK) orow[start + s1] = 1.0f;
}

extern "C" void kernel_launch(void* const* d_in, const int* in_sizes, int n_in,
                              void* d_out, int out_size, void* d_ws, size_t ws_size,
                              hipStream_t stream)
{
    const float* X  = (const float*)d_in[0];
    const float* Wq = (const float*)d_in[1];
    const float* bq = (const float*)d_in[2];
    const float* Wk = (const float*)d_in[3];
    const float* bk = (const float*)d_in[4];
    const int* nnpg = (const int*)d_in[5];
    const int* nrel = (const int*)d_in[6];

    const int n = in_sizes[0] / NF;
    const int n_graphs = in_sizes[5];

    float* Qb = (float*)d_ws;                 // [n][256] row-major
    float* Kt = Qb + (size_t)n * HD;          // [256][n] transposed
    float* out = (float*)d_out;

    dim3 gg(n / GR, 2);
    qk_gemm_kernel<<<gg, 256, 0, stream>>>(X, Wq, bq, Wk, bk, Qb, Kt, n);

    fill_zero_kernel<<<2048, 256, 0, stream>>>((float4*)out, out_size >> 2);

    attn_topk_kernel<<<n / NPB, NPB * 64, 0, stream>>>(Qb, Kt, nnpg, n_graphs, nrel, out, n);
}

// Round 6
// 154.516 us; speedup vs baseline: 1.1144x; 1.1144x over previous
//
#include <hip/hip_runtime.h>

#define NF    256   // IN_F
#define HD    256   // H*D
#define NH    4
#define DH    64
#define WINS  128   // WIN
#define HALFW 64
#define TOPK  32
#define NB    4     // nodes per attn block
#define GROWS 32    // rows per gemm block (4 waves x 8 rows)

__device__ __forceinline__ float readlane_f(float v, int l) {
    return __uint_as_float(__builtin_amdgcn_readlane(__float_as_uint(v), l));
}
__device__ __forceinline__ float getc(const float4& v, int j) {
    return j == 0 ? v.x : j == 1 ? v.y : j == 2 ? v.z : v.w;
}

// ------------- fused Q/K projection: X[n,256] @ W[256,256] + b -------------
// grid (n/GROWS, 2). Wave = 8 rows x 256 cols: lane owns cols 4l..4l+3.
// W: one coalesced b128 per (k): full 1KB row per wave instr, reused by 8 rows.
// X: wave-uniform scalar loads (s_load) via readfirstlane-forced base.
__global__ __launch_bounds__(256) void qk_gemm_kernel(
    const float* __restrict__ X,
    const float* __restrict__ Wq, const float* __restrict__ bq,
    const float* __restrict__ Wk, const float* __restrict__ bk,
    float* __restrict__ Qb, float* __restrict__ Kt, int n)
{
    const int t    = threadIdx.x;
    const int wave = t >> 6;
    const int lane = t & 63;
    const bool isK = (blockIdx.y != 0);
    const float* W   = isK ? Wk : Wq;
    const float* bia = isK ? bk : bq;

    const int r0  = blockIdx.x * GROWS + wave * 8;
    const int r0s = __builtin_amdgcn_readfirstlane(r0);
    const float* X0 = X + (size_t)r0s * NF;          // scalar base -> s_load

    float4 acc[8];
#pragma unroll
    for (int rr = 0; rr < 8; ++rr) acc[rr] = make_float4(0.f, 0.f, 0.f, 0.f);

    for (int k = 0; k < NF; k += 8) {
        float4 wv[8];
#pragma unroll
        for (int u = 0; u < 8; ++u)
            wv[u] = *(const float4*)(W + (size_t)(k + u) * HD + 4 * lane);
#pragma unroll
        for (int u = 0; u < 8; ++u) {
#pragma unroll
            for (int rr = 0; rr < 8; ++rr) {
                float xk = X0[rr * NF + k + u];      // SGPR broadcast
                acc[rr].x += xk * wv[u].x;
                acc[rr].y += xk * wv[u].y;
                acc[rr].z += xk * wv[u].z;
                acc[rr].w += xk * wv[u].w;
            }
        }
    }

    const float4 bv = *(const float4*)(bia + 4 * lane);
#pragma unroll
    for (int rr = 0; rr < 8; ++rr) {
        acc[rr].x += bv.x; acc[rr].y += bv.y; acc[rr].z += bv.z; acc[rr].w += bv.w;
    }

    if (!isK) {
#pragma unroll
        for (int rr = 0; rr < 8; ++rr)
            *(float4*)(Qb + (size_t)(r0 + rr) * HD + 4 * lane) = acc[rr];
    } else {
        // transposed: Kt[col][row], row-stride n. Lane stores 4 cols x 8 rows.
#pragma unroll
        for (int j = 0; j < 4; ++j) {
            int col = 4 * lane + j;
            float4 lo = make_float4(getc(acc[0], j), getc(acc[1], j),
                                    getc(acc[2], j), getc(acc[3], j));
            float4 hi = make_float4(getc(acc[4], j), getc(acc[5], j),
                                    getc(acc[6], j), getc(acc[7], j));
            *(float4*)(Kt + (size_t)col * n + r0)     = lo;
            *(float4*)(Kt + (size_t)col * n + r0 + 4) = hi;
        }
    }
}

// ---------------------- streaming zero-fill of output ----------------------
__global__ __launch_bounds__(256) void fill_zero_kernel(float4* __restrict__ p, int n4)
{
    int idx = blockIdx.x * 256 + threadIdx.x;
    int stride = gridDim.x * 256;
    float4 z = make_float4(0.f, 0.f, 0.f, 0.f);
    for (int c = idx; c < n4; c += stride) p[c] = z;
}

// ---- attention: block = NB=4 nodes, wave = head. Lane owns union cols
// 4l..4l+3 (float4 KT loads, each value reused by 4 nodes). Softmax with
// closed-form zero-pad handling; rank-count top-32; scatter 1.0s. ----
__global__ __launch_bounds__(256) void attn_topk_kernel(
    const float* __restrict__ Q,
    const float* __restrict__ KT,
    const int* __restrict__ nnpg, int n_graphs,
    const int* __restrict__ nrel,
    float* __restrict__ out, int n)
{
    const int t    = threadIdx.x;
    const int wave = t >> 6;
    const int lane = t & 63;
    const int i0   = blockIdx.x * NB;

    __shared__ float pslab[NH][NB][WINS];   // per-head probs in slot space
    __shared__ float attnv[NB][WINS];

    // per-node segment bounds: tile(nnpg, R) -> cumsum -> searchsorted(right)
    int st[NB], en[NB];
    {
        int R = nrel[0];
        int total = n_graphs * R;
#pragma unroll
        for (int nn = 0; nn < NB; ++nn) {
            int i = i0 + nn, ss = 0, se = n, cum = 0;
            for (int e = 0; e < total; ++e) {
                int sz = nnpg[e % n_graphs];
                int nc = cum + sz;
                if (i < nc) { ss = cum; se = nc; break; }
                cum = nc;
            }
            st[nn] = max(ss, i - HALFW);
            en[nn] = min(se, i + HALFW);
        }
    }
    const int u0 = (min(min(st[0], st[1]), min(st[2], st[3]))) & ~3;  // b128 align
    const int Ue = max(max(en[0], en[1]), max(en[2], en[3]));
    const int U  = Ue - u0;                       // <= 134 -> <=34 active lanes

    // q registers: lane l holds q[node nn][head=wave, dim=l]
    float qreg[NB];
#pragma unroll
    for (int nn = 0; nn < NB; ++nn)
        qreg[nn] = Q[(size_t)(i0 + nn) * HD + wave * DH + lane];

    float4 acc[NB];
#pragma unroll
    for (int nn = 0; nn < NB; ++nn) acc[nn] = make_float4(0.f, 0.f, 0.f, 0.f);

    const bool act = (4 * lane < U);
    const float* kb = KT + (size_t)(wave * DH) * n + u0 + 4 * lane;

    for (int d0 = 0; d0 < DH; d0 += 8) {
        float4 kv[8];
#pragma unroll
        for (int u = 0; u < 8; ++u)
            kv[u] = act ? *(const float4*)(kb + (size_t)(d0 + u) * n)
                        : make_float4(0.f, 0.f, 0.f, 0.f);
#pragma unroll
        for (int u = 0; u < 8; ++u) {
#pragma unroll
            for (int nn = 0; nn < NB; ++nn) {
                float qd = readlane_f(qreg[nn], d0 + u);
                acc[nn].x += qd * kv[u].x;
                acc[nn].y += qd * kv[u].y;
                acc[nn].z += qd * kv[u].z;
                acc[nn].w += qd * kv[u].w;
            }
        }
    }

    // per-(head, node) softmax over the 128-slot window incl. zero pads
#pragma unroll
    for (int nn = 0; nn < NB; ++nn) {
        const int rs  = st[nn] - u0;
        const int re  = en[nn] - u0;
        const int win = en[nn] - st[nn];          // >= 64 here
        float s[4]; bool v[4];
#pragma unroll
        for (int j = 0; j < 4; ++j) {
            int c = 4 * lane + j;
            v[j] = (c >= rs) && (c < re);
            s[j] = getc(acc[nn], j) * 0.25f;      // /sqrt(64)/tau
        }
        float lm = -1e30f;
#pragma unroll
        for (int j = 0; j < 4; ++j) if (v[j]) lm = fmaxf(lm, s[j]);
#pragma unroll
        for (int off = 32; off > 0; off >>= 1) lm = fmaxf(lm, __shfl_xor(lm, off));
        if (win < WINS) lm = fmaxf(lm, 0.f);      // pad slots have score 0
        float p[4], ls = 0.f;
#pragma unroll
        for (int j = 0; j < 4; ++j) {
            p[j] = v[j] ? expf(s[j] - lm) : 0.f;
            ls += p[j];
        }
#pragma unroll
        for (int off = 32; off > 0; off >>= 1) ls += __shfl_xor(ls, off);
        ls += (float)(WINS - win) * expf(-lm);    // pad contributions
        float inv = 1.f / ls;
#pragma unroll
        for (int j = 0; j < 4; ++j) {
            int c = 4 * lane + j;
            if (v[j]) pslab[wave][nn][c - rs] = p[j] * inv;
        }
    }
    __syncthreads();

    // combine heads (wave = node), mask pads, rank-count, scatter
    {
        const int nn = wave;
        int stn = st[0], enn = en[0];
        if (nn == 1) { stn = st[1]; enn = en[1]; }
        if (nn == 2) { stn = st[2]; enn = en[2]; }
        if (nn == 3) { stn = st[3]; enn = en[3]; }
        const int win = enn - stn;

        float a0 = (lane < win)
            ? 0.25f * (pslab[0][nn][lane] + pslab[1][nn][lane] +
                       pslab[2][nn][lane] + pslab[3][nn][lane]) : -1.0f;
        float a1 = (lane + 64 < win)
            ? 0.25f * (pslab[0][nn][lane + 64] + pslab[1][nn][lane + 64] +
                       pslab[2][nn][lane + 64] + pslab[3][nn][lane + 64]) : -1.0f;
        attnv[nn][lane]      = a0;
        attnv[nn][lane + 64] = a1;
    }
    __syncthreads();

    {
        const int nn = wave;
        int stn = st[0], enn = en[0];
        if (nn == 1) { stn = st[1]; enn = en[1]; }
        if (nn == 2) { stn = st[2]; enn = en[2]; }
        if (nn == 3) { stn = st[3]; enn = en[3]; }
        const int win = enn - stn;

        const float w0v = attnv[nn][lane];
        const float w1v = attnv[nn][lane + 64];
        const int s0 = lane, s1 = lane + 64;
        int cnt0 = 0, cnt1 = 0;
#pragma unroll
        for (int j4 = 0; j4 < WINS / 4; ++j4) {
            float4 a4 = *(const float4*)&attnv[nn][j4 * 4];   // broadcast b128
            int jb = j4 * 4;
            cnt0 += (a4.x > w0v) || (a4.x == w0v && (jb + 0) < s0);
            cnt0 += (a4.y > w0v) || (a4.y == w0v && (jb + 1) < s0);
            cnt0 += (a4.z > w0v) || (a4.z == w0v && (jb + 2) < s0);
            cnt0 += (a4.w > w0v) || (a4.w == w0v && (jb + 3) < s0);
            cnt1 += (a4.x > w1v) || (a4.x == w1v && (jb + 0) < s1);
            cnt1 += (a4.y > w1v) || (a4.y == w1v && (jb + 1) < s1);
            cnt1 += (a4.z > w1v) || (a4.z == w1v && (jb + 2) < s1);
            cnt1 += (a4.w > w1v) || (a4.w == w1v && (jb + 3) < s1);
        }
        float* orow = out + (size_t)(i0 + nn) * n;
        if (s0 < win && cnt0 < TOPK) orow[stn + s0] = 1.0f;
        if (s1 < win && cnt1 < TOPK) orow[stn + s1] = 1.0f;
    }
}

extern "C" void kernel_launch(void* const* d_in, const int* in_sizes, int n_in,
                              void* d_out, int out_size, void* d_ws, size_t ws_size,
                              hipStream_t stream)
{
    const float* X  = (const float*)d_in[0];
    const float* Wq = (const float*)d_in[1];
    const float* bq = (const float*)d_in[2];
    const float* Wk = (const float*)d_in[3];
    const float* bk = (const float*)d_in[4];
    const int* nnpg = (const int*)d_in[5];
    const int* nrel = (const int*)d_in[6];

    const int n = in_sizes[0] / NF;
    const int n_graphs = in_sizes[5];

    // Kt FIRST so its <=12B tail overread lands inside Qb (in-bounds, masked)
    float* Kt = (float*)d_ws;                 // [256][n] transposed
    float* Qb = Kt + (size_t)n * HD;          // [n][256] row-major
    float* out = (float*)d_out;

    dim3 gg(n / GROWS, 2);
    qk_gemm_kernel<<<gg, 256, 0, stream>>>(X, Wq, bq, Wk, bk, Qb, Kt, n);

    fill_zero_kernel<<<2048, 256, 0, stream>>>((float4*)out, out_size >> 2);

    attn_topk_kernel<<<n / NB, 256, 0, stream>>>(Qb, Kt, nnpg, n_graphs, nrel, out, n);
}